// Round 12
// baseline (347.704 us; speedup 1.0000x reference)
//
#include <hip/hip_runtime.h>

#define S_LEN  4096
#define DMODEL 1024
#define NHEAD  16
#define HDIM   64

// 0.125 (1/sqrt(HDIM)) * log2(e): folded into Q at projection time so the
// attention softmax is a bare v_exp_f32 (2^x) with no per-entry scale mul.
#define QSCALE 0.18033688011112042f

typedef unsigned short u16;
typedef unsigned int   u32;
typedef __bf16 bf16x8 __attribute__((ext_vector_type(8)));
typedef float  f32x4  __attribute__((ext_vector_type(4)));

static __device__ __forceinline__ u16 f2b(float f) {
    union { __bf16 b; u16 u; } c; c.b = (__bf16)f; return c.u;
}

static __device__ __forceinline__ float fexp2(float x) {
#if __has_builtin(__builtin_amdgcn_exp2f)
    return __builtin_amdgcn_exp2f(x);
#else
    return __expf(x * 0.6931471805599453f);
#endif
}

typedef __attribute__((address_space(3))) u32 lds_u32_t;
typedef __attribute__((address_space(1))) const u32 glb_u32_t;
static __device__ __forceinline__ void gload_lds16(const u16* g, u16* l) {
    __builtin_amdgcn_global_load_lds((glb_u32_t*)g, (lds_u32_t*)l, 16, 0, 0);
}

// ---------------------------------------------------------------------------
__global__ __launch_bounds__(256)
void convert_x(const float* __restrict__ x, u16* __restrict__ xb) {
    const int i0 = (blockIdx.x * 256 + threadIdx.x) * 8;
    float4 a = *reinterpret_cast<const float4*>(x + i0);
    float4 b = *reinterpret_cast<const float4*>(x + i0 + 4);
    u16 o[8] = {f2b(a.x), f2b(a.y), f2b(a.z), f2b(a.w),
                f2b(b.x), f2b(b.y), f2b(b.z), f2b(b.w)};
    *reinterpret_cast<uint4*>(xb + i0) = *reinterpret_cast<uint4*>(o);
}

// all 4 weights in one launch (z selects tensor)
__global__ __launch_bounds__(256)
void transpose_w4(const float* __restrict__ w0, const float* __restrict__ w1,
                  const float* __restrict__ w2, const float* __restrict__ w3,
                  u16* __restrict__ wT) {
    const int z = blockIdx.z;
    const float* w = (z == 0) ? w0 : (z == 1) ? w1 : (z == 2) ? w2 : w3;
    u16* dst0 = wT + (size_t)z * DMODEL * DMODEL;
    const int k0 = blockIdx.x * 64, n0 = blockIdx.y * 64;
    const int t = threadIdx.x;
    __shared__ u16 T[64][72];
    const int kk = t >> 4, nn = (t & 15) * 4;
    #pragma unroll
    for (int i = 0; i < 4; ++i) {
        float4 v = *reinterpret_cast<const float4*>(w + (size_t)(k0 + kk + i * 16) * DMODEL + n0 + nn);
        T[nn + 0][kk + i * 16] = f2b(v.x);
        T[nn + 1][kk + i * 16] = f2b(v.y);
        T[nn + 2][kk + i * 16] = f2b(v.z);
        T[nn + 3][kk + i * 16] = f2b(v.w);
    }
    __syncthreads();
    const int n = t >> 2, kc = (t & 3) * 16;
    uint4 r0 = *reinterpret_cast<const uint4*>(&T[n][kc]);
    uint4 r1 = *reinterpret_cast<const uint4*>(&T[n][kc + 8]);
    u16* dst = dst0 + (size_t)(n0 + n) * DMODEL + k0 + kc;
    *reinterpret_cast<uint4*>(dst)     = r0;
    *reinterpret_cast<uint4*>(dst + 8) = r1;
}

// ---------------------------------------------------------------------------
// QKV projection GEMM, 128x128 tiles (m97 structure), R8-exact.
//  - tz 0,1 (Q,K): scalar u16 stores, lanes 0-15 consecutive d (coalesced).
//    Q scaled by QSCALE.
//  - tz 2 (V): transposed [h][64][S]; 4 consecutive S-rows -> uint2.
__global__ __launch_bounds__(256, 2)
void gemm_qkv(const u16* __restrict__ A, const u16* __restrict__ BT,
              const float* __restrict__ b0, const float* __restrict__ b1,
              const float* __restrict__ b2, u16* __restrict__ Cout) {
    const int m0 = blockIdx.x * 128;
    const int ny = blockIdx.y;
    const int tz = ny >> 3;
    const int n0 = (ny & 7) * 128;
    const int tid = threadIdx.x, lane = tid & 63, w = tid >> 6;
    const int wr = w >> 1, wc = w & 1;
    const int fm = lane & 15, fq = lane >> 4;

    __shared__ u16 As[128][32];
    __shared__ u16 Bs[128][32];

    const u16* Bb = BT + (size_t)tz * DMODEL * DMODEL;

    f32x4 acc[4][4];
    #pragma unroll
    for (int i = 0; i < 4; ++i)
        #pragma unroll
        for (int t = 0; t < 4; ++t) acc[i][t] = f32x4{0.f, 0.f, 0.f, 0.f};

    const int srow = lane >> 2, scol = (lane & 3) * 8;

    for (int k0 = 0; k0 < DMODEL; k0 += 32) {
        #pragma unroll
        for (int r = 0; r < 2; ++r) {
            const int rowA = w * 32 + r * 16;
            gload_lds16(A  + (size_t)(m0 + rowA + srow) * DMODEL + k0 + scol, &As[rowA][0]);
            gload_lds16(Bb + (size_t)(n0 + rowA + srow) * DMODEL + k0 + scol, &Bs[rowA][0]);
        }
        __syncthreads();
        bf16x8 af[4], bf[4];
        #pragma unroll
        for (int i = 0; i < 4; ++i) af[i] = *reinterpret_cast<const bf16x8*>(&As[wr * 64 + i * 16 + fm][fq * 8]);
        #pragma unroll
        for (int t = 0; t < 4; ++t) bf[t] = *reinterpret_cast<const bf16x8*>(&Bs[wc * 64 + t * 16 + fm][fq * 8]);
        #pragma unroll
        for (int i = 0; i < 4; ++i)
            #pragma unroll
            for (int t = 0; t < 4; ++t)
                acc[i][t] = __builtin_amdgcn_mfma_f32_16x16x32_bf16(af[i], bf[t], acc[i][t], 0, 0, 0);
        __syncthreads();
    }

    const float* bp = (tz == 0) ? b0 : (tz == 1) ? b1 : b2;
    u16* base = Cout + (size_t)tz * S_LEN * DMODEL;
    const float scl = (tz == 0) ? QSCALE : 1.0f;
    #pragma unroll
    for (int t = 0; t < 4; ++t) {
        const int col = n0 + wc * 64 + t * 16 + fm;
        const int hh = col >> 6, d = col & 63;
        const float bias = bp[col];
        if (tz == 2) {
            // V transposed [h][d][S]: 4 consecutive S-rows at fixed d -> uint2
            u16* vb = base + ((size_t)hh * HDIM + d) * S_LEN;
            #pragma unroll
            for (int i = 0; i < 4; ++i) {
                const int row0 = m0 + wr * 64 + i * 16 + fq * 4;
                u16 o[4] = {f2b(acc[i][t][0] + bias), f2b(acc[i][t][1] + bias),
                            f2b(acc[i][t][2] + bias), f2b(acc[i][t][3] + bias)};
                *reinterpret_cast<uint2*>(vb + row0) = *reinterpret_cast<uint2*>(o);
            }
        } else {
            #pragma unroll
            for (int i = 0; i < 4; ++i) {
                #pragma unroll
                for (int r = 0; r < 4; ++r) {
                    const int row = m0 + wr * 64 + i * 16 + fq * 4 + r;
                    base[((size_t)hh * S_LEN + row) * HDIM + d] =
                        f2b((acc[i][t][r] + bias) * scl);
                }
            }
        }
    }
}

// ---------------------------------------------------------------------------
// Output projection GEMM, 128x64 tiles, grid (32,16)=512 = 2 blocks/CU.
// R8-exact: scalar f32 stores, lanes 0-15 consecutive cols (coalesced).
__global__ __launch_bounds__(256, 2)
void gemm_o(const u16* __restrict__ A, const u16* __restrict__ BT,
            const float* __restrict__ bias, float* __restrict__ C) {
    const int m0 = blockIdx.x * 128;
    const int n0 = blockIdx.y * 64;
    const int tid = threadIdx.x, lane = tid & 63, w = tid >> 6;
    const int fm = lane & 15, fq = lane >> 4;

    __shared__ u16 As[128][32];
    __shared__ u16 Bs[64][32];

    f32x4 acc[2][4];
    #pragma unroll
    for (int i = 0; i < 2; ++i)
        #pragma unroll
        for (int t = 0; t < 4; ++t) acc[i][t] = f32x4{0.f, 0.f, 0.f, 0.f};

    const int srow = lane >> 2, scol = (lane & 3) * 8;

    for (int k0 = 0; k0 < DMODEL; k0 += 32) {
        #pragma unroll
        for (int r = 0; r < 2; ++r) {
            const int rowA = w * 32 + r * 16;
            gload_lds16(A + (size_t)(m0 + rowA + srow) * DMODEL + k0 + scol, &As[rowA][0]);
        }
        gload_lds16(BT + (size_t)(n0 + w * 16 + srow) * DMODEL + k0 + scol, &Bs[w * 16][0]);
        __syncthreads();
        bf16x8 af[2], bf[4];
        #pragma unroll
        for (int i = 0; i < 2; ++i) af[i] = *reinterpret_cast<const bf16x8*>(&As[w * 32 + i * 16 + fm][fq * 8]);
        #pragma unroll
        for (int t = 0; t < 4; ++t) bf[t] = *reinterpret_cast<const bf16x8*>(&Bs[t * 16 + fm][fq * 8]);
        #pragma unroll
        for (int i = 0; i < 2; ++i)
            #pragma unroll
            for (int t = 0; t < 4; ++t)
                acc[i][t] = __builtin_amdgcn_mfma_f32_16x16x32_bf16(af[i], bf[t], acc[i][t], 0, 0, 0);
        __syncthreads();
    }

    #pragma unroll
    for (int t = 0; t < 4; ++t) {
        const int col = n0 + t * 16 + fm;
        const float b = bias[col];
        #pragma unroll
        for (int i = 0; i < 2; ++i) {
            #pragma unroll
            for (int r = 0; r < 4; ++r) {
                const int row = m0 + w * 32 + i * 16 + fq * 4 + r;
                C[(size_t)row * DMODEL + col] = acc[i][t][r] + b;
            }
        }
    }
}

// ---------------------------------------------------------------------------
// Flash attention v9: V from L2 (per-wave register fragments), K double-buffer
// in LDS, ONE barrier/iter.
//  - V^T [h][64][S] is L2-resident (XCD swizzle, FETCH 14.4 MB measured).
//    PV B-operand bytes = Vh[(t*16+fm)*S + kt*64 + ph*32 + fq*8] -> load
//    directly as uint4 per (t,ph); issue ph0 at iter top, ph1 after QK^T
//    (latency hidden under barrier+QK^T+softmax). No Vt staging / ds_reads.
//  - Freed LDS: Ks double-buffers (2x8.5KB) + Pt 9.2KB = 26.6KB (unchanged).
//    2-deep K buffer -> ONE barrier/iter is race-free: barrier(i) guarantees
//    all waves finished compute(i-1) before any wave stages Ks[p] at i+1.
//  - P redistribution via wave-private Pt round-trip (R8-proven; R11's shfl
//    alternative = ds_bpermute crossbar, 8.4M bank conflicts, -29 us).
//  - NSPLIT=2 KV-split, XCD-swizzled 1D grid, setprio on MFMA clusters.
template<int NSPLIT>
__global__ __launch_bounds__(256, 4)
void attn_kernel(const u16* __restrict__ Q, const u16* __restrict__ K,
                 const u16* __restrict__ V, void* __restrict__ Optr,
                 float* __restrict__ Lp) {
    int qt, h, sp;
    if (NSPLIT > 1) {
        const int bid = blockIdx.x;
        const int xcd = bid & 7;
        const int g = bid >> 3;
        qt = g & 31;
        const int hs = g >> 5;            // 0..3
        h = xcd | ((hs & 1) << 3);
        sp = hs >> 1;
    } else {
        qt = blockIdx.x; h = blockIdx.y; sp = 0;
    }
    const int tid = threadIdx.x, lane = tid & 63, wid = tid >> 6;
    const int fm = lane & 15, fq = lane >> 4;

    __shared__ alignas(16) u16 Pt[128][36];     // [q][key half], wave-private
    __shared__ alignas(16) u16 Ks[2][64][68];   // [key][d], double buffer

    const u16* Qh = Q + (size_t)h * S_LEN * HDIM;
    const u16* Kh = K + (size_t)h * S_LEN * HDIM;
    const u16* Vh = V + (size_t)h * S_LEN * HDIM;   // [64][S] transposed

    const int srow = tid >> 2, sch = (tid & 3) * 16;   // K staging

    // Q fragments in registers (B-operand of S^T: fixed q=fm, contiguous d)
    bf16x8 qf[2][2];
    #pragma unroll
    for (int rb = 0; rb < 2; ++rb) {
        const u16* qsrc = Qh + (size_t)(qt * 128 + wid * 32 + rb * 16 + fm) * HDIM + fq * 8;
        qf[rb][0] = *reinterpret_cast<const bf16x8*>(qsrc);
        qf[rb][1] = *reinterpret_cast<const bf16x8*>(qsrc + 32);
    }

    float rsum[2] = {0.f, 0.f};
    f32x4 oacc[2][4];
    #pragma unroll
    for (int rb = 0; rb < 2; ++rb)
        #pragma unroll
        for (int t = 0; t < 4; ++t) oacc[rb][t] = f32x4{0.f, 0.f, 0.f, 0.f};

    const int TOT  = S_LEN / 64;
    const int NT   = TOT / NSPLIT;
    const int kt0  = sp * NT;

    // per-lane V base: row d = fm (+16t handled by offset), key offset fq*8
    const u16* vbase = Vh + (size_t)fm * S_LEN + (size_t)kt0 * 64 + fq * 8;

    uint4 kr0, kr1;
    {
        const u16* ks = Kh + (size_t)(kt0 * 64 + srow) * HDIM + sch;
        kr0 = *reinterpret_cast<const uint4*>(ks);
        kr1 = *reinterpret_cast<const uint4*>(ks + 8);
    }

    union vu { uint4 q; bf16x8 v; };

    for (int it = 0; it < NT; ++it) {
        const int kt = kt0 + it;
        const int p = it & 1;

        // issue V loads for ph=0 (L2-resident; latency hides under barrier+QK^T)
        vu v0[4];
        #pragma unroll
        for (int t = 0; t < 4; ++t)
            v0[t].q = *reinterpret_cast<const uint4*>(vbase + (size_t)(t * 16) * S_LEN);

        // stage K tile (data prefetched last iter)
        *reinterpret_cast<uint4*>(&Ks[p][srow][sch])     = kr0;
        *reinterpret_cast<uint4*>(&Ks[p][srow][sch + 8]) = kr1;
        __syncthreads();                       // staging visible; 2-deep safe

        if (it + 1 < NT) {                     // prefetch next K tile
            const u16* ks = Kh + (size_t)((kt + 1) * 64 + srow) * HDIM + sch;
            kr0 = *reinterpret_cast<const uint4*>(ks);
            kr1 = *reinterpret_cast<const uint4*>(ks + 8);
        }

        // S^T = K * Q^T : row = key (mt*16 + fq*4 + r), col = q (fm).
        f32x4 sacc[2][4];
        #pragma unroll
        for (int rb = 0; rb < 2; ++rb)
            #pragma unroll
            for (int mt = 0; mt < 4; ++mt) sacc[rb][mt] = f32x4{0.f, 0.f, 0.f, 0.f};
        __builtin_amdgcn_s_setprio(1);
        #pragma unroll
        for (int kk2 = 0; kk2 < 2; ++kk2) {
            #pragma unroll
            for (int mt = 0; mt < 4; ++mt) {
                bf16x8 kf = *reinterpret_cast<const bf16x8*>(&Ks[p][mt * 16 + fm][kk2 * 32 + fq * 8]);
                #pragma unroll
                for (int rb = 0; rb < 2; ++rb)
                    sacc[rb][mt] = __builtin_amdgcn_mfma_f32_16x16x32_bf16(kf, qf[rb][kk2], sacc[rb][mt], 0, 0, 0);
            }
        }
        __builtin_amdgcn_s_setprio(0);

        // issue V loads for ph=1 (used after ph=0's softmax+PV)
        vu v1[4];
        #pragma unroll
        for (int t = 0; t < 4; ++t)
            v1[t].q = *reinterpret_cast<const uint4*>(vbase + (size_t)(t * 16) * S_LEN + 32);

        // Two phases: P-half write (mt pair) -> PV on that key half.
        // Pt rows are wave-private; DS ops complete in order -> no barrier.
        #pragma unroll
        for (int ph = 0; ph < 2; ++ph) {
            #pragma unroll
            for (int rb = 0; rb < 2; ++rb) {
                #pragma unroll
                for (int m2 = 0; m2 < 2; ++m2) {
                    const int mt = ph * 2 + m2;
                    u32 pk[2];
                    float e0 = fexp2(sacc[rb][mt][0]);
                    float e1 = fexp2(sacc[rb][mt][1]);
                    float e2 = fexp2(sacc[rb][mt][2]);
                    float e3 = fexp2(sacc[rb][mt][3]);
                    rsum[rb] += (e0 + e1) + (e2 + e3);
                    pk[0] = (u32)f2b(e0) | ((u32)f2b(e1) << 16);
                    pk[1] = (u32)f2b(e2) | ((u32)f2b(e3) << 16);
                    *reinterpret_cast<uint2*>(&Pt[wid * 32 + rb * 16 + fm][m2 * 16 + fq * 4]) =
                        uint2{pk[0], pk[1]};
                }
            }
            bf16x8 af[2];
            #pragma unroll
            for (int rb = 0; rb < 2; ++rb)
                af[rb] = *reinterpret_cast<const bf16x8*>(&Pt[wid * 32 + rb * 16 + fm][fq * 8]);
            __builtin_amdgcn_s_setprio(1);
            #pragma unroll
            for (int t = 0; t < 4; ++t) {
                bf16x8 bfv = (ph == 0) ? v0[t].v : v1[t].v;
                #pragma unroll
                for (int rb = 0; rb < 2; ++rb)
                    oacc[rb][t] = __builtin_amdgcn_mfma_f32_16x16x32_bf16(af[rb], bfv, oacc[rb][t], 0, 0, 0);
            }
            __builtin_amdgcn_s_setprio(0);
        }

        vbase += 64;                           // next key tile
    }

    if (NSPLIT > 1) {
        // unnormalized f32 partials + per-row denominator
        float* Op = (float*)Optr + (size_t)sp * S_LEN * DMODEL;
        #pragma unroll
        for (int rb = 0; rb < 2; ++rb) {
            float rs = rsum[rb];
            rs += __shfl_xor(rs, 16, 64);
            rs += __shfl_xor(rs, 32, 64);
            if (fq == 0)
                Lp[(size_t)sp * NHEAD * S_LEN + (size_t)h * S_LEN +
                   qt * 128 + wid * 32 + rb * 16 + fm] = rs;
            #pragma unroll
            for (int t = 0; t < 4; ++t) {
                const int d = t * 16 + fm;
                #pragma unroll
                for (int r = 0; r < 4; ++r) {
                    const int row = qt * 128 + wid * 32 + rb * 16 + fq * 4 + r;
                    Op[(size_t)row * DMODEL + h * HDIM + d] = oacc[rb][t][r];
                }
            }
        }
    } else {
        float l[2][4];
        #pragma unroll
        for (int rb = 0; rb < 2; ++rb) {
            float rs = rsum[rb];
            rs += __shfl_xor(rs, 16, 64);
            rs += __shfl_xor(rs, 32, 64);
            #pragma unroll
            for (int r = 0; r < 4; ++r) l[rb][r] = __shfl(rs, fq * 4 + r, 64);
        }
        u16* O = (u16*)Optr;
        #pragma unroll
        for (int rb = 0; rb < 2; ++rb)
            #pragma unroll
            for (int t = 0; t < 4; ++t) {
                const int d = t * 16 + fm;
                #pragma unroll
                for (int r = 0; r < 4; ++r) {
                    const int row = qt * 128 + wid * 32 + rb * 16 + fq * 4 + r;
                    O[(size_t)row * DMODEL + h * HDIM + d] = f2b(oacc[rb][t][r] / l[rb][r]);
                }
            }
    }
}

// ---------------------------------------------------------------------------
// sum_s(O_s) / sum_s(l_s) -> bf16, elementwise over [4096][1024]
template<int NS>
__global__ __launch_bounds__(256)
void combine_o(const float* __restrict__ Op, const float* __restrict__ Lp,
               u16* __restrict__ Ob) {
    const size_t i = ((size_t)blockIdx.x * 256 + threadIdx.x) * 4;
    const int row = (int)(i >> 10), col = (int)(i & 1023);
    const int h = col >> 6;
    float ax = 0.f, ay = 0.f, az = 0.f, aw = 0.f, l = 0.f;
    #pragma unroll
    for (int s = 0; s < NS; ++s) {
        float4 v = *reinterpret_cast<const float4*>(Op + (size_t)s * S_LEN * DMODEL + i);
        ax += v.x; ay += v.y; az += v.z; aw += v.w;
        l += Lp[(size_t)s * NHEAD * S_LEN + (size_t)h * S_LEN + row];
    }
    const float inv = 1.0f / l;
    u16 o[4] = {f2b(ax * inv), f2b(ay * inv), f2b(az * inv), f2b(aw * inv)};
    *reinterpret_cast<uint2*>(Ob + i) = *reinterpret_cast<uint2*>(o);
}

extern "C" void kernel_launch(void* const* d_in, const int* in_sizes, int n_in,
                              void* d_out, int out_size, void* d_ws, size_t ws_size,
                              hipStream_t stream) {
    const float* x  = (const float*)d_in[0];
    const float* wq = (const float*)d_in[1];
    const float* bq = (const float*)d_in[2];
    const float* wk = (const float*)d_in[3];
    const float* bk = (const float*)d_in[4];
    const float* wv = (const float*)d_in[5];
    const float* bv = (const float*)d_in[6];
    const float* wo = (const float*)d_in[7];
    const float* bo = (const float*)d_in[8];

    u16* ws = (u16*)d_ws;
    const size_t MW  = (size_t)DMODEL * DMODEL;
    const size_t NX  = (size_t)S_LEN * DMODEL;
    const size_t TSZ = (size_t)NHEAD * S_LEN * HDIM;

    u16* xb = ws;
    u16* WT = xb + NX;
    u16* Qb = WT + 4 * MW;
    u16* Ob = Qb + 3 * TSZ;
    float* Op = (float*)(Ob + NX);               // 2 * NX f32 partials
    float* Lp2 = Op + (size_t)2 * NX;            // 2 * NHEAD * S_LEN f32 sums
    const size_t need2 = (size_t)((char*)(Lp2 + (size_t)2 * NHEAD * S_LEN) - (char*)d_ws);

    hipLaunchKernelGGL(convert_x, dim3(NX / 2048), dim3(256), 0, stream, x, xb);
    hipLaunchKernelGGL(transpose_w4, dim3(16, 16, 4), dim3(256), 0, stream, wq, wk, wv, wo, WT);

    hipLaunchKernelGGL(gemm_qkv, dim3(S_LEN / 128, 24), dim3(256), 0, stream,
                       xb, WT, bq, bk, bv, Qb);

    if (ws_size >= need2) {
        hipLaunchKernelGGL((attn_kernel<2>), dim3(1024), dim3(256), 0, stream,
                           Qb, Qb + TSZ, Qb + 2 * TSZ, (void*)Op, Lp2);
        hipLaunchKernelGGL((combine_o<2>), dim3((S_LEN * DMODEL / 4) / 256), dim3(256), 0, stream,
                           Op, Lp2, Ob);
    } else {
        hipLaunchKernelGGL((attn_kernel<1>), dim3(S_LEN / 128, NHEAD), dim3(256), 0, stream,
                           Qb, Qb + TSZ, Qb + 2 * TSZ, (void*)Ob, (float*)nullptr);
    }

    hipLaunchKernelGGL(gemm_o, dim3(S_LEN / 128, DMODEL / 64), dim3(256), 0, stream,
                       Ob, WT + 3 * MW, bo, (float*)d_out);
}

// Round 13
// 241.656 us; speedup vs baseline: 1.4388x; 1.4388x over previous
//
#include <hip/hip_runtime.h>

#define S_LEN  4096
#define DMODEL 1024
#define NHEAD  16
#define HDIM   64

// 0.125 (1/sqrt(HDIM)) * log2(e): folded into Q at projection time so the
// attention softmax is a bare v_exp_f32 (2^x) with no per-entry scale mul.
#define QSCALE 0.18033688011112042f

typedef unsigned short u16;
typedef unsigned int   u32;
typedef __bf16 bf16x8 __attribute__((ext_vector_type(8)));
typedef float  f32x4  __attribute__((ext_vector_type(4)));

static __device__ __forceinline__ u16 f2b(float f) {
    union { __bf16 b; u16 u; } c; c.b = (__bf16)f; return c.u;
}

static __device__ __forceinline__ float fexp2(float x) {
#if __has_builtin(__builtin_amdgcn_exp2f)
    return __builtin_amdgcn_exp2f(x);
#else
    // exp(x*ln2) == 2^x ; __expf is the known-good fast path in this harness
    return __expf(x * 0.6931471805599453f);
#endif
}

typedef __attribute__((address_space(3))) u32 lds_u32_t;
typedef __attribute__((address_space(1))) const u32 glb_u32_t;
static __device__ __forceinline__ void gload_lds16(const u16* g, u16* l) {
    __builtin_amdgcn_global_load_lds((glb_u32_t*)g, (lds_u32_t*)l, 16, 0, 0);
}

// ---------------------------------------------------------------------------
__global__ __launch_bounds__(256)
void convert_x(const float* __restrict__ x, u16* __restrict__ xb) {
    const int i0 = (blockIdx.x * 256 + threadIdx.x) * 8;
    float4 a = *reinterpret_cast<const float4*>(x + i0);
    float4 b = *reinterpret_cast<const float4*>(x + i0 + 4);
    u16 o[8] = {f2b(a.x), f2b(a.y), f2b(a.z), f2b(a.w),
                f2b(b.x), f2b(b.y), f2b(b.z), f2b(b.w)};
    *reinterpret_cast<uint4*>(xb + i0) = *reinterpret_cast<uint4*>(o);
}

// all 4 weights in one launch (z selects tensor)
__global__ __launch_bounds__(256)
void transpose_w4(const float* __restrict__ w0, const float* __restrict__ w1,
                  const float* __restrict__ w2, const float* __restrict__ w3,
                  u16* __restrict__ wT) {
    const int z = blockIdx.z;
    const float* w = (z == 0) ? w0 : (z == 1) ? w1 : (z == 2) ? w2 : w3;
    u16* dst0 = wT + (size_t)z * DMODEL * DMODEL;
    const int k0 = blockIdx.x * 64, n0 = blockIdx.y * 64;
    const int t = threadIdx.x;
    __shared__ u16 T[64][72];
    const int kk = t >> 4, nn = (t & 15) * 4;
    #pragma unroll
    for (int i = 0; i < 4; ++i) {
        float4 v = *reinterpret_cast<const float4*>(w + (size_t)(k0 + kk + i * 16) * DMODEL + n0 + nn);
        T[nn + 0][kk + i * 16] = f2b(v.x);
        T[nn + 1][kk + i * 16] = f2b(v.y);
        T[nn + 2][kk + i * 16] = f2b(v.z);
        T[nn + 3][kk + i * 16] = f2b(v.w);
    }
    __syncthreads();
    const int n = t >> 2, kc = (t & 3) * 16;
    uint4 r0 = *reinterpret_cast<const uint4*>(&T[n][kc]);
    uint4 r1 = *reinterpret_cast<const uint4*>(&T[n][kc + 8]);
    u16* dst = dst0 + (size_t)(n0 + n) * DMODEL + k0 + kc;
    *reinterpret_cast<uint4*>(dst)     = r0;
    *reinterpret_cast<uint4*>(dst + 8) = r1;
}

// ---------------------------------------------------------------------------
// QKV projection GEMM, 128x128 tiles (m97 structure), R8-exact.
//  - tz 0,1 (Q,K): scalar u16 stores, lanes 0-15 consecutive d (coalesced).
//    Q scaled by QSCALE.
//  - tz 2 (V): transposed [h][64][S]; 4 consecutive S-rows -> uint2.
__global__ __launch_bounds__(256, 2)
void gemm_qkv(const u16* __restrict__ A, const u16* __restrict__ BT,
              const float* __restrict__ b0, const float* __restrict__ b1,
              const float* __restrict__ b2, u16* __restrict__ Cout) {
    const int m0 = blockIdx.x * 128;
    const int ny = blockIdx.y;
    const int tz = ny >> 3;
    const int n0 = (ny & 7) * 128;
    const int tid = threadIdx.x, lane = tid & 63, w = tid >> 6;
    const int wr = w >> 1, wc = w & 1;
    const int fm = lane & 15, fq = lane >> 4;

    __shared__ u16 As[128][32];
    __shared__ u16 Bs[128][32];

    const u16* Bb = BT + (size_t)tz * DMODEL * DMODEL;

    f32x4 acc[4][4];
    #pragma unroll
    for (int i = 0; i < 4; ++i)
        #pragma unroll
        for (int t = 0; t < 4; ++t) acc[i][t] = f32x4{0.f, 0.f, 0.f, 0.f};

    const int srow = lane >> 2, scol = (lane & 3) * 8;

    for (int k0 = 0; k0 < DMODEL; k0 += 32) {
        #pragma unroll
        for (int r = 0; r < 2; ++r) {
            const int rowA = w * 32 + r * 16;
            gload_lds16(A  + (size_t)(m0 + rowA + srow) * DMODEL + k0 + scol, &As[rowA][0]);
            gload_lds16(Bb + (size_t)(n0 + rowA + srow) * DMODEL + k0 + scol, &Bs[rowA][0]);
        }
        __syncthreads();
        bf16x8 af[4], bf[4];
        #pragma unroll
        for (int i = 0; i < 4; ++i) af[i] = *reinterpret_cast<const bf16x8*>(&As[wr * 64 + i * 16 + fm][fq * 8]);
        #pragma unroll
        for (int t = 0; t < 4; ++t) bf[t] = *reinterpret_cast<const bf16x8*>(&Bs[wc * 64 + t * 16 + fm][fq * 8]);
        #pragma unroll
        for (int i = 0; i < 4; ++i)
            #pragma unroll
            for (int t = 0; t < 4; ++t)
                acc[i][t] = __builtin_amdgcn_mfma_f32_16x16x32_bf16(af[i], bf[t], acc[i][t], 0, 0, 0);
        __syncthreads();
    }

    const float* bp = (tz == 0) ? b0 : (tz == 1) ? b1 : b2;
    u16* base = Cout + (size_t)tz * S_LEN * DMODEL;
    const float scl = (tz == 0) ? QSCALE : 1.0f;
    #pragma unroll
    for (int t = 0; t < 4; ++t) {
        const int col = n0 + wc * 64 + t * 16 + fm;
        const int hh = col >> 6, d = col & 63;
        const float bias = bp[col];
        if (tz == 2) {
            // V transposed [h][d][S]: 4 consecutive S-rows at fixed d -> uint2
            u16* vb = base + ((size_t)hh * HDIM + d) * S_LEN;
            #pragma unroll
            for (int i = 0; i < 4; ++i) {
                const int row0 = m0 + wr * 64 + i * 16 + fq * 4;
                u16 o[4] = {f2b(acc[i][t][0] + bias), f2b(acc[i][t][1] + bias),
                            f2b(acc[i][t][2] + bias), f2b(acc[i][t][3] + bias)};
                *reinterpret_cast<uint2*>(vb + row0) = *reinterpret_cast<uint2*>(o);
            }
        } else {
            #pragma unroll
            for (int i = 0; i < 4; ++i) {
                #pragma unroll
                for (int r = 0; r < 4; ++r) {
                    const int row = m0 + wr * 64 + i * 16 + fq * 4 + r;
                    base[((size_t)hh * S_LEN + row) * HDIM + d] =
                        f2b((acc[i][t][r] + bias) * scl);
                }
            }
        }
    }
}

// ---------------------------------------------------------------------------
// Output projection GEMM, 128x64 tiles, grid (32,16)=512 = 2 blocks/CU
// (the 128x128 version ran 1 block/CU = zero wave overlap). R8-exact:
// scalar f32 stores, lanes 0-15 consecutive cols (coalesced).
__global__ __launch_bounds__(256, 2)
void gemm_o(const u16* __restrict__ A, const u16* __restrict__ BT,
            const float* __restrict__ bias, float* __restrict__ C) {
    const int m0 = blockIdx.x * 128;
    const int n0 = blockIdx.y * 64;
    const int tid = threadIdx.x, lane = tid & 63, w = tid >> 6;
    const int fm = lane & 15, fq = lane >> 4;

    __shared__ u16 As[128][32];
    __shared__ u16 Bs[64][32];

    f32x4 acc[2][4];
    #pragma unroll
    for (int i = 0; i < 2; ++i)
        #pragma unroll
        for (int t = 0; t < 4; ++t) acc[i][t] = f32x4{0.f, 0.f, 0.f, 0.f};

    const int srow = lane >> 2, scol = (lane & 3) * 8;

    for (int k0 = 0; k0 < DMODEL; k0 += 32) {
        #pragma unroll
        for (int r = 0; r < 2; ++r) {
            const int rowA = w * 32 + r * 16;
            gload_lds16(A + (size_t)(m0 + rowA + srow) * DMODEL + k0 + scol, &As[rowA][0]);
        }
        gload_lds16(BT + (size_t)(n0 + w * 16 + srow) * DMODEL + k0 + scol, &Bs[w * 16][0]);
        __syncthreads();
        bf16x8 af[2], bf[4];
        #pragma unroll
        for (int i = 0; i < 2; ++i) af[i] = *reinterpret_cast<const bf16x8*>(&As[w * 32 + i * 16 + fm][fq * 8]);
        #pragma unroll
        for (int t = 0; t < 4; ++t) bf[t] = *reinterpret_cast<const bf16x8*>(&Bs[t * 16 + fm][fq * 8]);
        #pragma unroll
        for (int i = 0; i < 2; ++i)
            #pragma unroll
            for (int t = 0; t < 4; ++t)
                acc[i][t] = __builtin_amdgcn_mfma_f32_16x16x32_bf16(af[i], bf[t], acc[i][t], 0, 0, 0);
        __syncthreads();
    }

    #pragma unroll
    for (int t = 0; t < 4; ++t) {
        const int col = n0 + t * 16 + fm;
        const float b = bias[col];
        #pragma unroll
        for (int i = 0; i < 2; ++i) {
            #pragma unroll
            for (int r = 0; r < 4; ++r) {
                const int row = m0 + w * 32 + i * 16 + fq * 4 + r;
                C[(size_t)row * DMODEL + col] = acc[i][t][r] + b;
            }
        }
    }
}

// ---------------------------------------------------------------------------
// Flash attention (R8 frozen config, 106.4 us / FETCH 14.4 MB):
//  - NSPLIT=2 KV-split: 1024 blocks, all co-resident (4/CU). 1D grid with
//    bid&7 carrying the head's low 3 bits: each XCD sees only h in {x, x+8}
//    -> K/V/Q working set ~3 MB, L2-resident (FETCH 71.7 -> 14.4 MB measured).
//  - __launch_bounds__(256,4), VGPR=64; LDS 26 KB; half-size Pt;
//    V pre-transposed [h][64][S]; s_setprio around MFMA clusters.
//  - LDS round-trip for P is optimal here: R11's shfl alternative =
//    ds_bpermute crossbar (8.4M bank conflicts, -29 us); R12's V-from-L2 =
//    latency-bound (-110 us). Staging + ds_read_b128 amortizes latency.
template<int NSPLIT>
__global__ __launch_bounds__(256, 4)
void attn_kernel(const u16* __restrict__ Q, const u16* __restrict__ K,
                 const u16* __restrict__ V, void* __restrict__ Optr,
                 float* __restrict__ Lp) {
    int qt, h, sp;
    if (NSPLIT > 1) {
        const int bid = blockIdx.x;
        const int xcd = bid & 7;
        const int g = bid >> 3;
        qt = g & 31;
        const int hs = g >> 5;            // 0..3
        h = xcd | ((hs & 1) << 3);
        sp = hs >> 1;
    } else {
        qt = blockIdx.x; h = blockIdx.y; sp = 0;
    }
    const int tid = threadIdx.x, lane = tid & 63, wid = tid >> 6;
    const int fm = lane & 15, fq = lane >> 4;

    __shared__ alignas(16) u16 Pt[128][36];  // [q][key half-tile], wave-private
    __shared__ alignas(16) u16 Ks[64][68];   // [key][d]
    __shared__ alignas(16) u16 Vt[64][68];   // [d][key]

    const u16* Qh = Q + (size_t)h * S_LEN * HDIM;
    const u16* Kh = K + (size_t)h * S_LEN * HDIM;
    const u16* Vh = V + (size_t)h * S_LEN * HDIM;   // [64][S] transposed

    const int srow = tid >> 2, sch = (tid & 3) * 16;   // K and V staging

    // Q fragments in registers (B-operand of S^T: fixed q=fm, contiguous d)
    bf16x8 qf[2][2];
    #pragma unroll
    for (int rb = 0; rb < 2; ++rb) {
        const u16* qsrc = Qh + (size_t)(qt * 128 + wid * 32 + rb * 16 + fm) * HDIM + fq * 8;
        qf[rb][0] = *reinterpret_cast<const bf16x8*>(qsrc);
        qf[rb][1] = *reinterpret_cast<const bf16x8*>(qsrc + 32);
    }

    float rsum[2] = {0.f, 0.f};
    f32x4 oacc[2][4];
    #pragma unroll
    for (int rb = 0; rb < 2; ++rb)
        #pragma unroll
        for (int t = 0; t < 4; ++t) oacc[rb][t] = f32x4{0.f, 0.f, 0.f, 0.f};

    const int TOT  = S_LEN / 64;
    const int NT   = TOT / NSPLIT;
    const int kt0  = sp * NT;

    uint4 kr0, kr1, vr0, vr1;
    {
        const u16* ks = Kh + (size_t)(kt0 * 64 + srow) * HDIM + sch;
        kr0 = *reinterpret_cast<const uint4*>(ks);
        kr1 = *reinterpret_cast<const uint4*>(ks + 8);
        const u16* vs = Vh + (size_t)srow * S_LEN + kt0 * 64 + sch;
        vr0 = *reinterpret_cast<const uint4*>(vs);
        vr1 = *reinterpret_cast<const uint4*>(vs + 8);
    }

    for (int it = 0; it < NT; ++it) {
        const int kt = kt0 + it;
        __syncthreads();                       // readers of prev tile done
        *reinterpret_cast<uint4*>(&Ks[srow][sch])     = kr0;
        *reinterpret_cast<uint4*>(&Ks[srow][sch + 8]) = kr1;
        *reinterpret_cast<uint4*>(&Vt[srow][sch])     = vr0;
        *reinterpret_cast<uint4*>(&Vt[srow][sch + 8]) = vr1;
        __syncthreads();                       // staging visible

        if (it + 1 < NT) {                     // prefetch overlaps compute
            const u16* ks = Kh + (size_t)((kt + 1) * 64 + srow) * HDIM + sch;
            kr0 = *reinterpret_cast<const uint4*>(ks);
            kr1 = *reinterpret_cast<const uint4*>(ks + 8);
            const u16* vs = Vh + (size_t)srow * S_LEN + (kt + 1) * 64 + sch;
            vr0 = *reinterpret_cast<const uint4*>(vs);
            vr1 = *reinterpret_cast<const uint4*>(vs + 8);
        }

        // S^T = K * Q^T : row = key (mt*16 + fq*4 + r), col = q (fm).
        f32x4 sacc[2][4];
        #pragma unroll
        for (int rb = 0; rb < 2; ++rb)
            #pragma unroll
            for (int mt = 0; mt < 4; ++mt) sacc[rb][mt] = f32x4{0.f, 0.f, 0.f, 0.f};
        __builtin_amdgcn_s_setprio(1);
        #pragma unroll
        for (int kk2 = 0; kk2 < 2; ++kk2) {
            #pragma unroll
            for (int mt = 0; mt < 4; ++mt) {
                bf16x8 kf = *reinterpret_cast<const bf16x8*>(&Ks[mt * 16 + fm][kk2 * 32 + fq * 8]);
                #pragma unroll
                for (int rb = 0; rb < 2; ++rb)
                    sacc[rb][mt] = __builtin_amdgcn_mfma_f32_16x16x32_bf16(kf, qf[rb][kk2], sacc[rb][mt], 0, 0, 0);
            }
        }
        __builtin_amdgcn_s_setprio(0);

        // Two phases: P-half write (mt pair) -> PV on that key half.
        // Pt rows are wave-private; DS ops complete in order -> no barrier.
        #pragma unroll
        for (int ph = 0; ph < 2; ++ph) {
            #pragma unroll
            for (int rb = 0; rb < 2; ++rb) {
                #pragma unroll
                for (int m2 = 0; m2 < 2; ++m2) {
                    const int mt = ph * 2 + m2;
                    u32 pk[2];
                    float e0 = fexp2(sacc[rb][mt][0]);
                    float e1 = fexp2(sacc[rb][mt][1]);
                    float e2 = fexp2(sacc[rb][mt][2]);
                    float e3 = fexp2(sacc[rb][mt][3]);
                    rsum[rb] += (e0 + e1) + (e2 + e3);
                    pk[0] = (u32)f2b(e0) | ((u32)f2b(e1) << 16);
                    pk[1] = (u32)f2b(e2) | ((u32)f2b(e3) << 16);
                    *reinterpret_cast<uint2*>(&Pt[wid * 32 + rb * 16 + fm][m2 * 16 + fq * 4]) =
                        uint2{pk[0], pk[1]};
                }
            }
            bf16x8 af[2];
            #pragma unroll
            for (int rb = 0; rb < 2; ++rb)
                af[rb] = *reinterpret_cast<const bf16x8*>(&Pt[wid * 32 + rb * 16 + fm][fq * 8]);
            __builtin_amdgcn_s_setprio(1);
            #pragma unroll
            for (int t = 0; t < 4; ++t) {
                bf16x8 bf = *reinterpret_cast<const bf16x8*>(&Vt[t * 16 + fm][ph * 32 + fq * 8]);
                #pragma unroll
                for (int rb = 0; rb < 2; ++rb)
                    oacc[rb][t] = __builtin_amdgcn_mfma_f32_16x16x32_bf16(af[rb], bf, oacc[rb][t], 0, 0, 0);
            }
            __builtin_amdgcn_s_setprio(0);
        }
    }

    if (NSPLIT > 1) {
        // unnormalized f32 partials + per-row denominator
        float* Op = (float*)Optr + (size_t)sp * S_LEN * DMODEL;
        #pragma unroll
        for (int rb = 0; rb < 2; ++rb) {
            float rs = rsum[rb];
            rs += __shfl_xor(rs, 16, 64);
            rs += __shfl_xor(rs, 32, 64);
            if (fq == 0)
                Lp[(size_t)sp * NHEAD * S_LEN + (size_t)h * S_LEN +
                   qt * 128 + wid * 32 + rb * 16 + fm] = rs;
            #pragma unroll
            for (int t = 0; t < 4; ++t) {
                const int d = t * 16 + fm;
                #pragma unroll
                for (int r = 0; r < 4; ++r) {
                    const int row = qt * 128 + wid * 32 + rb * 16 + fq * 4 + r;
                    Op[(size_t)row * DMODEL + h * HDIM + d] = oacc[rb][t][r];
                }
            }
        }
    } else {
        float l[2][4];
        #pragma unroll
        for (int rb = 0; rb < 2; ++rb) {
            float rs = rsum[rb];
            rs += __shfl_xor(rs, 16, 64);
            rs += __shfl_xor(rs, 32, 64);
            #pragma unroll
            for (int r = 0; r < 4; ++r) l[rb][r] = __shfl(rs, fq * 4 + r, 64);
        }
        u16* O = (u16*)Optr;
        #pragma unroll
        for (int rb = 0; rb < 2; ++rb)
            #pragma unroll
            for (int t = 0; t < 4; ++t) {
                const int d = t * 16 + fm;
                #pragma unroll
                for (int r = 0; r < 4; ++r) {
                    const int row = qt * 128 + wid * 32 + rb * 16 + fq * 4 + r;
                    O[(size_t)row * DMODEL + h * HDIM + d] = f2b(oacc[rb][t][r] / l[rb][r]);
                }
            }
    }
}

// ---------------------------------------------------------------------------
// sum_s(O_s) / sum_s(l_s) -> bf16, elementwise over [4096][1024]
template<int NS>
__global__ __launch_bounds__(256)
void combine_o(const float* __restrict__ Op, const float* __restrict__ Lp,
               u16* __restrict__ Ob) {
    const size_t i = ((size_t)blockIdx.x * 256 + threadIdx.x) * 4;
    const int row = (int)(i >> 10), col = (int)(i & 1023);
    const int h = col >> 6;
    float ax = 0.f, ay = 0.f, az = 0.f, aw = 0.f, l = 0.f;
    #pragma unroll
    for (int s = 0; s < NS; ++s) {
        float4 v = *reinterpret_cast<const float4*>(Op + (size_t)s * S_LEN * DMODEL + i);
        ax += v.x; ay += v.y; az += v.z; aw += v.w;
        l += Lp[(size_t)s * NHEAD * S_LEN + (size_t)h * S_LEN + row];
    }
    const float inv = 1.0f / l;
    u16 o[4] = {f2b(ax * inv), f2b(ay * inv), f2b(az * inv), f2b(aw * inv)};
    *reinterpret_cast<uint2*>(Ob + i) = *reinterpret_cast<uint2*>(o);
}

extern "C" void kernel_launch(void* const* d_in, const int* in_sizes, int n_in,
                              void* d_out, int out_size, void* d_ws, size_t ws_size,
                              hipStream_t stream) {
    const float* x  = (const float*)d_in[0];
    const float* wq = (const float*)d_in[1];
    const float* bq = (const float*)d_in[2];
    const float* wk = (const float*)d_in[3];
    const float* bk = (const float*)d_in[4];
    const float* wv = (const float*)d_in[5];
    const float* bv = (const float*)d_in[6];
    const float* wo = (const float*)d_in[7];
    const float* bo = (const float*)d_in[8];

    u16* ws = (u16*)d_ws;
    const size_t MW  = (size_t)DMODEL * DMODEL;
    const size_t NX  = (size_t)S_LEN * DMODEL;
    const size_t TSZ = (size_t)NHEAD * S_LEN * HDIM;

    u16* xb = ws;
    u16* WT = xb + NX;
    u16* Qb = WT + 4 * MW;
    u16* Ob = Qb + 3 * TSZ;
    float* Op = (float*)(Ob + NX);               // 2 * NX f32 partials
    float* Lp2 = Op + (size_t)2 * NX;            // 2 * NHEAD * S_LEN f32 sums
    const size_t need2 = (size_t)((char*)(Lp2 + (size_t)2 * NHEAD * S_LEN) - (char*)d_ws);

    hipLaunchKernelGGL(convert_x, dim3(NX / 2048), dim3(256), 0, stream, x, xb);
    hipLaunchKernelGGL(transpose_w4, dim3(16, 16, 4), dim3(256), 0, stream, wq, wk, wv, wo, WT);

    hipLaunchKernelGGL(gemm_qkv, dim3(S_LEN / 128, 24), dim3(256), 0, stream,
                       xb, WT, bq, bk, bv, Qb);

    if (ws_size >= need2) {
        hipLaunchKernelGGL((attn_kernel<2>), dim3(1024), dim3(256), 0, stream,
                           Qb, Qb + TSZ, Qb + 2 * TSZ, (void*)Op, Lp2);
        hipLaunchKernelGGL((combine_o<2>), dim3((S_LEN * DMODEL / 4) / 256), dim3(256), 0, stream,
                           Op, Lp2, Ob);
    } else {
        hipLaunchKernelGGL((attn_kernel<1>), dim3(S_LEN / 128, NHEAD), dim3(256), 0, stream,
                           Qb, Qb + TSZ, Qb + 2 * TSZ, (void*)Ob, (float*)nullptr);
    }

    hipLaunchKernelGGL(gemm_o, dim3(S_LEN / 128, DMODEL / 64), dim3(256), 0, stream,
                       Ob, WT + 3 * MW, bo, (float*)d_out);
}